// Round 1
// baseline (253.055 us; speedup 1.0000x reference)
//
#include <hip/hip_runtime.h>

// Problem constants (from reference): B=16, T=512, D=8576.
#define N_ROWS 8192            // B*T
#define D_CH   8576
#define DV     (D_CH / 4)      // 2144 float4 columns
#define STATS_ROWS_PER_BLOCK 64
#define STATS_ROW_CHUNKS (N_ROWS / STATS_ROWS_PER_BLOCK)   // 128
#define APPLY_ROWS_PER_BLOCK 32
#define APPLY_ROW_CHUNKS (N_ROWS / APPLY_ROWS_PER_BLOCK)   // 256
#define EPSV 1e-5f
#define NOISE_STD 0.05f

// ws layout (floats): [0,D) sum | [D,2D) sumsq | [2D,3D) scale | [3D,4D) shift
// scale/shift region starts at byte offset 2*D*4 = 68608 (16B aligned -> float4 ok)

__global__ __launch_bounds__(256) void bn_partial_stats(
    const float4* __restrict__ x, float* __restrict__ ws_sum, float* __restrict__ ws_sq)
{
    int vc = blockIdx.x * blockDim.x + threadIdx.x;   // vec-channel
    if (vc >= DV) return;
    size_t base = (size_t)blockIdx.y * STATS_ROWS_PER_BLOCK * DV + vc;
    float4 s = make_float4(0.f, 0.f, 0.f, 0.f);
    float4 q = make_float4(0.f, 0.f, 0.f, 0.f);
#pragma unroll 4
    for (int r = 0; r < STATS_ROWS_PER_BLOCK; ++r) {
        float4 v = x[base + (size_t)r * DV];
        s.x += v.x; s.y += v.y; s.z += v.z; s.w += v.w;
        q.x += v.x * v.x; q.y += v.y * v.y; q.z += v.z * v.z; q.w += v.w * v.w;
    }
    int d0 = vc * 4;
    atomicAdd(&ws_sum[d0 + 0], s.x);
    atomicAdd(&ws_sum[d0 + 1], s.y);
    atomicAdd(&ws_sum[d0 + 2], s.z);
    atomicAdd(&ws_sum[d0 + 3], s.w);
    atomicAdd(&ws_sq[d0 + 0], q.x);
    atomicAdd(&ws_sq[d0 + 1], q.y);
    atomicAdd(&ws_sq[d0 + 2], q.z);
    atomicAdd(&ws_sq[d0 + 3], q.w);
}

__global__ __launch_bounds__(256) void bn_finalize(
    const float* __restrict__ ws_sum, const float* __restrict__ ws_sq,
    const float* __restrict__ gamma, const float* __restrict__ beta,
    float* __restrict__ ws_scale, float* __restrict__ ws_shift)
{
    int d = blockIdx.x * blockDim.x + threadIdx.x;
    if (d >= D_CH) return;
    const float invN = 1.0f / (float)N_ROWS;
    float mu  = ws_sum[d] * invN;
    float var = ws_sq[d] * invN - mu * mu;
    float sc  = gamma[d] * rsqrtf(var + EPSV);
    ws_scale[d] = sc;
    ws_shift[d] = beta[d] - mu * sc;
}

__global__ __launch_bounds__(256) void bn_apply(
    const float4* __restrict__ x, const float4* __restrict__ noise,
    const float4* __restrict__ ws_scale4, const float4* __restrict__ ws_shift4,
    float4* __restrict__ out)
{
    int vc = blockIdx.x * blockDim.x + threadIdx.x;
    if (vc >= DV) return;
    float4 sc = ws_scale4[vc];
    float4 sh = ws_shift4[vc];
    size_t base = (size_t)blockIdx.y * APPLY_ROWS_PER_BLOCK * DV + vc;
#pragma unroll 4
    for (int r = 0; r < APPLY_ROWS_PER_BLOCK; ++r) {
        size_t idx = base + (size_t)r * DV;
        float4 xv = x[idx];
        float4 nv = noise[idx];
        float4 o;
        o.x = fmaf(xv.x, sc.x, sh.x) + nv.x * NOISE_STD;
        o.y = fmaf(xv.y, sc.y, sh.y) + nv.y * NOISE_STD;
        o.z = fmaf(xv.z, sc.z, sh.z) + nv.z * NOISE_STD;
        o.w = fmaf(xv.w, sc.w, sh.w) + nv.w * NOISE_STD;
        out[idx] = o;
    }
}

extern "C" void kernel_launch(void* const* d_in, const int* in_sizes, int n_in,
                              void* d_out, int out_size, void* d_ws, size_t ws_size,
                              hipStream_t stream) {
    const float* x     = (const float*)d_in[0];
    const float* noise = (const float*)d_in[1];
    const float* gamma = (const float*)d_in[2];
    const float* beta  = (const float*)d_in[3];
    float* out = (float*)d_out;

    float* ws      = (float*)d_ws;
    float* ws_sum   = ws;
    float* ws_sq    = ws + D_CH;
    float* ws_scale = ws + 2 * D_CH;
    float* ws_shift = ws + 3 * D_CH;

    // Zero the accumulators (stream-ordered, capture-safe).
    hipMemsetAsync(d_ws, 0, 2 * D_CH * sizeof(float), stream);

    dim3 blk(256, 1, 1);
    dim3 grd_stats((DV + 255) / 256, STATS_ROW_CHUNKS, 1);   // 9 x 128
    bn_partial_stats<<<grd_stats, blk, 0, stream>>>((const float4*)x, ws_sum, ws_sq);

    dim3 grd_fin((D_CH + 255) / 256, 1, 1);                  // 34
    bn_finalize<<<grd_fin, blk, 0, stream>>>(ws_sum, ws_sq, gamma, beta, ws_scale, ws_shift);

    dim3 grd_apply((DV + 255) / 256, APPLY_ROW_CHUNKS, 1);   // 9 x 256
    bn_apply<<<grd_apply, blk, 0, stream>>>((const float4*)x, (const float4*)noise,
                                            (const float4*)ws_scale, (const float4*)ws_shift,
                                            (float4*)out);
}

// Round 3
// 220.349 us; speedup vs baseline: 1.1484x; 1.1484x over previous
//
#include <hip/hip_runtime.h>

// Problem constants (from reference): B=16, T=512, D=8576.
#define N_ROWS 8192            // B*T
#define D_CH   8576
#define DV     (D_CH / 4)      // 2144 float4 columns
#define STATS_ROWS_PER_BLOCK 32
#define STATS_ROW_CHUNKS (N_ROWS / STATS_ROWS_PER_BLOCK)   // 256
#define APPLY_ROWS_PER_BLOCK 16
#define APPLY_ROW_CHUNKS (N_ROWS / APPLY_ROWS_PER_BLOCK)   // 512
#define EPSV 1e-5f
#define NOISE_STD 0.05f

typedef float f32x4 __attribute__((ext_vector_type(4)));   // native vector: OK for nontemporal builtins

// ws layout (floats): [0,D) sum | [D,2D) sumsq | [2D,3D) scale | [3D,4D) shift

__global__ __launch_bounds__(256) void bn_partial_stats(
    const f32x4* __restrict__ x, float* __restrict__ ws_sum, float* __restrict__ ws_sq)
{
    int vc = blockIdx.x * blockDim.x + threadIdx.x;   // vec-channel
    if (vc >= DV) return;
    size_t base = (size_t)blockIdx.y * STATS_ROWS_PER_BLOCK * DV + vc;
    // two independent accumulator pairs for ILP
    f32x4 s0 = (f32x4)0.f, s1 = (f32x4)0.f;
    f32x4 q0 = (f32x4)0.f, q1 = (f32x4)0.f;
#pragma unroll 4
    for (int r = 0; r < STATS_ROWS_PER_BLOCK; r += 2) {
        f32x4 a = x[base + (size_t)r * DV];
        f32x4 b = x[base + (size_t)(r + 1) * DV];
        s0 += a;
        q0 += a * a;
        s1 += b;
        q1 += b * b;
    }
    f32x4 s = s0 + s1;
    f32x4 q = q0 + q1;
    int d0 = vc * 4;
    atomicAdd(&ws_sum[d0 + 0], s.x);
    atomicAdd(&ws_sum[d0 + 1], s.y);
    atomicAdd(&ws_sum[d0 + 2], s.z);
    atomicAdd(&ws_sum[d0 + 3], s.w);
    atomicAdd(&ws_sq[d0 + 0], q.x);
    atomicAdd(&ws_sq[d0 + 1], q.y);
    atomicAdd(&ws_sq[d0 + 2], q.z);
    atomicAdd(&ws_sq[d0 + 3], q.w);
}

__global__ __launch_bounds__(256) void bn_finalize(
    const float* __restrict__ ws_sum, const float* __restrict__ ws_sq,
    const float* __restrict__ gamma, const float* __restrict__ beta,
    float* __restrict__ ws_scale, float* __restrict__ ws_shift)
{
    int d = blockIdx.x * blockDim.x + threadIdx.x;
    if (d >= D_CH) return;
    const float invN = 1.0f / (float)N_ROWS;
    float mu  = ws_sum[d] * invN;
    float var = ws_sq[d] * invN - mu * mu;
    float sc  = gamma[d] * rsqrtf(var + EPSV);
    ws_scale[d] = sc;
    ws_shift[d] = beta[d] - mu * sc;
}

__global__ __launch_bounds__(256) void bn_apply(
    const f32x4* __restrict__ x, const f32x4* __restrict__ noise,
    const f32x4* __restrict__ ws_scale4, const f32x4* __restrict__ ws_shift4,
    f32x4* __restrict__ out)
{
    int vc = blockIdx.x * blockDim.x + threadIdx.x;
    if (vc >= DV) return;
    f32x4 sc = ws_scale4[vc];
    f32x4 sh = ws_shift4[vc];
    size_t base = (size_t)blockIdx.y * APPLY_ROWS_PER_BLOCK * DV + vc;
#pragma unroll 8
    for (int r = 0; r < APPLY_ROWS_PER_BLOCK; ++r) {
        size_t idx = base + (size_t)r * DV;
        f32x4 xv = __builtin_nontemporal_load(&x[idx]);
        f32x4 nv = __builtin_nontemporal_load(&noise[idx]);
        f32x4 o = xv * sc + sh + nv * NOISE_STD;
        __builtin_nontemporal_store(o, &out[idx]);
    }
}

extern "C" void kernel_launch(void* const* d_in, const int* in_sizes, int n_in,
                              void* d_out, int out_size, void* d_ws, size_t ws_size,
                              hipStream_t stream) {
    const float* x     = (const float*)d_in[0];
    const float* noise = (const float*)d_in[1];
    const float* gamma = (const float*)d_in[2];
    const float* beta  = (const float*)d_in[3];
    float* out = (float*)d_out;

    float* ws       = (float*)d_ws;
    float* ws_sum   = ws;
    float* ws_sq    = ws + D_CH;
    float* ws_scale = ws + 2 * D_CH;
    float* ws_shift = ws + 3 * D_CH;

    // Zero the accumulators (stream-ordered, capture-safe).
    (void)hipMemsetAsync(d_ws, 0, 2 * D_CH * sizeof(float), stream);

    dim3 blk(256, 1, 1);
    dim3 grd_stats((DV + 255) / 256, STATS_ROW_CHUNKS, 1);   // 9 x 256
    bn_partial_stats<<<grd_stats, blk, 0, stream>>>((const f32x4*)x, ws_sum, ws_sq);

    dim3 grd_fin((D_CH + 255) / 256, 1, 1);                  // 34
    bn_finalize<<<grd_fin, blk, 0, stream>>>(ws_sum, ws_sq, gamma, beta, ws_scale, ws_shift);

    dim3 grd_apply((DV + 255) / 256, APPLY_ROW_CHUNKS, 1);   // 9 x 512
    bn_apply<<<grd_apply, blk, 0, stream>>>((const f32x4*)x, (const f32x4*)noise,
                                            (const f32x4*)ws_scale, (const f32x4*)ws_shift,
                                            (f32x4*)out);
}